// Round 7
// baseline (4696.299 us; speedup 1.0000x reference)
//
#include <hip/hip_runtime.h>
#include <math.h>

#define COMMITMENT_COST 0.25f
#define DECAY 0.99f
#define EPSILON 1e-05f
#define KCODES 1024
#define DIM 256
#define NTOK 32768

// out-buffer float offsets (concatenated return tuple)
#define O_QUANT 0
#define O_LOSS  8388608
#define O_IDX   8388609
#define O_CS    8421377
#define O_EMAW  8422401
#define O_EMB   8684545

// scratch in the new_embedding slot (262144 floats, written LAST by fin).
// O_EMB is odd -> +1 float makes packed u64 8-byte aligned.
#define SE_PACKED 1        // u64 x 32768 -> floats [1, 65537)
#define SE_ESQ    65544
#define SE_ZSQ    66568    // 32768 floats
#define SE_HIST   99336    // 1024 ints
#define SE_DONE   100360   // 1 int

// ------- pre: zsq, esq, zero dw/hist/done/loss, init packed -------
__global__ void pre_kernel(const float* __restrict__ z, const float* __restrict__ E,
                           float* __restrict__ zsq, float* __restrict__ esq,
                           float* __restrict__ dw, int* __restrict__ hist,
                           unsigned long long* __restrict__ packed,
                           int* __restrict__ done, float* __restrict__ loss) {
    const int b = blockIdx.x;
    const int wave = threadIdx.x >> 6;
    const int lane = threadIdx.x & 63;
    if (b < NTOK / 4) {
        int token = b * 4 + wave;
        float4 v = ((const float4*)(z + (size_t)token * DIM))[lane];
        float s = v.x * v.x + v.y * v.y + v.z * v.z + v.w * v.w;
        #pragma unroll
        for (int off = 32; off > 0; off >>= 1) s += __shfl_down(s, off);
        if (lane == 0) zsq[token] = s;
        if (threadIdx.x < 4) packed[b * 4 + threadIdx.x] = ~0ull;
        if (b == 0 && threadIdx.x == 4) { done[0] = 0; loss[0] = 0.0f; }
    } else {
        int eb = b - NTOK / 4;                 // 0..255
        int k = eb * 4 + wave;
        float4 v = ((const float4*)(E + (size_t)k * DIM))[lane];
        float s = v.x * v.x + v.y * v.y + v.z * v.z + v.w * v.w;
        #pragma unroll
        for (int off = 32; off > 0; off >>= 1) s += __shfl_down(s, off);
        if (lane == 0) esq[k] = s;
        float4 zero4 = {0.f, 0.f, 0.f, 0.f};
        ((float4*)dw)[eb * 256 + threadIdx.x] = zero4;
        if (threadIdx.x < 4) hist[eb * 4 + threadIdx.x] = 0;
    }
}

// ---------------- fused distances + argmin (K-split + atomicMin) ----------
// d = fl(fl(||z||^2 + ||e||^2) - 2*z.e); positive -> float-bit order works.
// Pack (dist_bits<<32)|idx, u64 atomicMin = global min w/ first-index ties.
// Accumulation order per (i,j) identical to the passing round: dc asc, dg
// asc, x,y,z,w -> distances bit-identical.
// block 256 thr; tile 128 tok x 128 codes (1 of 8 K-chunks); 32-d chunks.
// thread: r=tid>>4 (8 tokens), c=tid&15 (8 codes c+16j).
// zs: 32-f rows, XOR-swizzled (slot = cf4 ^ ((row>>3)&7)) -> zv reads
// conflict-free (4 distinct quads, 16-lane broadcast). es: 36-f rows ->
// ev reads 2-way (free). LDS 34.8 KB.
__global__ __launch_bounds__(256, 3) void dist_argmin_kernel(
        const float* __restrict__ z, const float* __restrict__ E,
        const float* __restrict__ esq, const float* __restrict__ zsq,
        unsigned long long* __restrict__ packed) {
    __shared__ float zs[128 * 32];
    __shared__ float es[128 * 36];

    const int tid = threadIdx.x;
    const int r = tid >> 4;          // 0..15 -> tokens r*8 .. r*8+7
    const int c = tid & 15;          // codes c + 16*j, j=0..7
    const int ks   = blockIdx.x & 7;
    const int tok0 = (blockIdx.x >> 3) * 128;
    const int k0   = ks * 128;

    float An[8], sq[8];
    #pragma unroll
    for (int i = 0; i < 8; ++i) An[i] = zsq[tok0 + r * 8 + i];
    #pragma unroll
    for (int j = 0; j < 8; ++j) sq[j] = esq[k0 + c + 16 * j];

    // staging: thread covers rows srow+32q, fixed f4-col scf4 (coalesced)
    const int srow = tid >> 3;       // 0..31
    const int scf4 = tid & 7;
    const float* zb = z + (size_t)(tok0 + srow) * DIM + scf4 * 4;
    const float* Eb = E + (size_t)(k0 + srow) * DIM + scf4 * 4;
    int zoff[4], eoff[4];
    #pragma unroll
    for (int q = 0; q < 4; ++q) {
        int row = srow + 32 * q;
        zoff[q] = row * 32 + ((scf4 ^ ((row >> 3) & 7)) << 2);
        eoff[q] = row * 36 + scf4 * 4;
    }

    float acc[8][8];
    #pragma unroll
    for (int i = 0; i < 8; ++i)
        #pragma unroll
        for (int j = 0; j < 8; ++j) acc[i][j] = 0.0f;

    float4 gz[4], ge[4];
    #pragma unroll
    for (int q = 0; q < 4; ++q) gz[q] = *(const float4*)(zb + (size_t)q * 32 * DIM);
    #pragma unroll
    for (int q = 0; q < 4; ++q) ge[q] = *(const float4*)(Eb + (size_t)q * 32 * DIM);
    #pragma unroll
    for (int q = 0; q < 4; ++q) *(float4*)(zs + zoff[q]) = gz[q];
    #pragma unroll
    for (int q = 0; q < 4; ++q) *(float4*)(es + eoff[q]) = ge[q];
    __syncthreads();

    for (int dc = 0; dc < 8; ++dc) {
        if (dc < 7) {                 // prefetch next chunk (overlaps compute)
            const int d0 = (dc + 1) * 32;
            #pragma unroll
            for (int q = 0; q < 4; ++q)
                gz[q] = *(const float4*)(zb + (size_t)q * 32 * DIM + d0);
            #pragma unroll
            for (int q = 0; q < 4; ++q)
                ge[q] = *(const float4*)(Eb + (size_t)q * 32 * DIM + d0);
        }
        #pragma unroll
        for (int dg = 0; dg < 8; ++dg) {
            float4 zv[8];
            #pragma unroll
            for (int i = 0; i < 8; ++i)
                zv[i] = *(const float4*)(zs + (r * 8 + i) * 32 +
                                         ((dg ^ (r & 7)) << 2));
            #pragma unroll
            for (int j = 0; j < 8; ++j) {
                float4 ev = *(const float4*)(es + (c + 16 * j) * 36 + dg * 4);
                #pragma unroll
                for (int i = 0; i < 8; ++i) {
                    acc[i][j] = fmaf(zv[i].x, ev.x, acc[i][j]);
                    acc[i][j] = fmaf(zv[i].y, ev.y, acc[i][j]);
                    acc[i][j] = fmaf(zv[i].z, ev.z, acc[i][j]);
                    acc[i][j] = fmaf(zv[i].w, ev.w, acc[i][j]);
                }
            }
        }
        if (dc < 7) {
            __syncthreads();
            #pragma unroll
            for (int q = 0; q < 4; ++q) *(float4*)(zs + zoff[q]) = gz[q];
            #pragma unroll
            for (int q = 0; q < 4; ++q) *(float4*)(es + eoff[q]) = ge[q];
            __syncthreads();
        }
    }
    // epilogue: mirror reference rounding sequence, local then cross-lane min
    #pragma unroll
    for (int i = 0; i < 8; ++i) {
        float v = 3.4e38f; int id = 0x7fffffff;
        #pragma unroll
        for (int j = 0; j < 8; ++j) {
            float S = An[i] + sq[j];
            float dv = S - 2.0f * acc[i][j];
            int gi = k0 + c + 16 * j;
            if (dv < v || (dv == v && gi < id)) { v = dv; id = gi; }
        }
        #pragma unroll
        for (int m = 1; m < 16; m <<= 1) {
            float ov = __shfl_xor(v, m);
            int   oi = __shfl_xor(id, m);
            if (ov < v || (ov == v && oi < id)) { v = ov; id = oi; }
        }
        if (c == 0) {
            unsigned long long p =
                ((unsigned long long)__float_as_uint(v) << 32) | (unsigned)id;
            atomicMin(&packed[tok0 + r * 8 + i], p);
        }
    }
}

// ------- mid: unpack idx, hist, quant gather, loss, dw atomics; -------
// ------- last block computes cluster-size (fenced done-counter).  -------
__global__ __launch_bounds__(256) void mid_kernel(
        const float* __restrict__ z, const float* __restrict__ E,
        const unsigned long long* __restrict__ packed,
        float* __restrict__ idx_out, int* __restrict__ hist,
        float* __restrict__ dw, float* __restrict__ quant,
        float* __restrict__ loss_acc, int* __restrict__ done,
        const float* __restrict__ ema_cs, float* __restrict__ cs_out) {
    __shared__ float ls[4];
    __shared__ int amlast;
    __shared__ float f[256];
    const int wave = threadIdx.x >> 6;
    const int lane = threadIdx.x & 63;
    const int token = blockIdx.x * 4 + wave;
    const int idx = (int)(unsigned)(packed[token] & 0xFFFFFFFFull);

    if (lane == 0) {
        idx_out[token] = (float)idx;
        atomicAdd(&hist[idx], 1);
    }

    const float4 ev = *(const float4*)(E + (size_t)idx * DIM + lane * 4);
    const float4 zv = *(const float4*)(z + (size_t)token * DIM + lane * 4);
    *(float4*)(quant + (size_t)token * DIM + lane * 4) = ev;

    float* dwp = dw + (size_t)idx * DIM + lane * 4;
    atomicAdd(dwp + 0, zv.x);
    atomicAdd(dwp + 1, zv.y);
    atomicAdd(dwp + 2, zv.z);
    atomicAdd(dwp + 3, zv.w);

    float dx = zv.x - ev.x, dy = zv.y - ev.y, dz = zv.z - ev.z, dww = zv.w - ev.w;
    float l = dx * dx + dy * dy + dz * dz + dww * dww;
    #pragma unroll
    for (int off = 32; off > 0; off >>= 1) l += __shfl_down(l, off);
    if (lane == 0) ls[wave] = l;
    __syncthreads();
    if (threadIdx.x == 0)
        atomicAdd(loss_acc, ls[0] + ls[1] + ls[2] + ls[3]);

    // last-block finale: cluster-size normalize
    __threadfence();
    __syncthreads();
    if (threadIdx.x == 0)
        amlast = (atomicAdd(done, 1) == (int)gridDim.x - 1);
    __syncthreads();
    if (amlast) {
        __threadfence();
        float pre4[4];
        float part = 0.0f;
        #pragma unroll
        for (int q = 0; q < 4; ++q) {
            int k = threadIdx.x * 4 + q;
            int cv = atomicAdd(&hist[k], 0);      // device-coherent read
            pre4[q] = ema_cs[k] * DECAY + (1.0f - DECAY) * (float)cv;
            part += pre4[q];
        }
        f[threadIdx.x] = part;
        __syncthreads();
        for (int s = 128; s > 0; s >>= 1) {
            if (threadIdx.x < s) f[threadIdx.x] += f[threadIdx.x + s];
            __syncthreads();
        }
        float n = f[0];
        #pragma unroll
        for (int q = 0; q < 4; ++q) {
            int k = threadIdx.x * 4 + q;
            cs_out[k] = (pre4[q] + EPSILON) / (n + KCODES * EPSILON) * n;
        }
    }
}

// ------- fin: new_ema_w & new_embedding (+ loss finalize) -------
__global__ __launch_bounds__(256) void fin_kernel(
        const float* __restrict__ ema_w, const float* __restrict__ cs,
        float* __restrict__ emaw_inout /* holds dw */, float* __restrict__ emb_out,
        float* __restrict__ loss_inout) {
    const int i = blockIdx.x * 256 + threadIdx.x;   // f4 index, 65536 total
    const int k = i >> 6;
    float4 d = ((const float4*)emaw_inout)[i];
    float4 w = ((const float4*)ema_w)[i];
    float4 nw;
    nw.x = w.x * DECAY + (1.0f - DECAY) * d.x;
    nw.y = w.y * DECAY + (1.0f - DECAY) * d.y;
    nw.z = w.z * DECAY + (1.0f - DECAY) * d.z;
    nw.w = w.w * DECAY + (1.0f - DECAY) * d.w;
    ((float4*)emaw_inout)[i] = nw;
    float inv = 1.0f / cs[k];
    float4 e; e.x = nw.x * inv; e.y = nw.y * inv; e.z = nw.z * inv; e.w = nw.w * inv;
    ((float4*)emb_out)[i] = e;
    if (i == 0)
        loss_inout[0] = COMMITMENT_COST * loss_inout[0] / (float)((size_t)NTOK * DIM);
}

extern "C" void kernel_launch(void* const* d_in, const int* in_sizes, int n_in,
                              void* d_out, int out_size, void* d_ws, size_t ws_size,
                              hipStream_t stream) {
    const float* z      = (const float*)d_in[0];
    const float* E      = (const float*)d_in[1];
    const float* ema_cs = (const float*)d_in[2];
    const float* ema_w  = (const float*)d_in[3];
    float* out = (float*)d_out;

    float* emb = out + O_EMB;
    unsigned long long* packed = (unsigned long long*)(emb + SE_PACKED);
    float* esq  = emb + SE_ESQ;
    float* zsq  = emb + SE_ZSQ;
    int*   hist = (int*)(emb + SE_HIST);
    int*   done = (int*)(emb + SE_DONE);

    pre_kernel<<<NTOK / 4 + KCODES / 4, 256, 0, stream>>>(
        z, E, zsq, esq, out + O_EMAW, hist, packed, done, out + O_LOSS);
    dist_argmin_kernel<<<(NTOK / 128) * 8, 256, 0, stream>>>(z, E, esq, zsq, packed);
    mid_kernel<<<NTOK / 4, 256, 0, stream>>>(z, E, packed, out + O_IDX, hist,
                                             out + O_EMAW, out + O_QUANT,
                                             out + O_LOSS, done, ema_cs, out + O_CS);
    fin_kernel<<<256, 256, 0, stream>>>(ema_w, out + O_CS, out + O_EMAW, emb,
                                        out + O_LOSS);
}

// Round 8
// 1068.535 us; speedup vs baseline: 4.3951x; 4.3951x over previous
//
#include <hip/hip_runtime.h>
#include <math.h>

#define COMMITMENT_COST 0.25f
#define DECAY 0.99f
#define EPSILON 1e-05f
#define KCODES 1024
#define DIM 256
#define NTOK 32768

// out-buffer float offsets (concatenated return tuple)
#define O_QUANT 0
#define O_LOSS  8388608
#define O_IDX   8388609
#define O_CS    8421377
#define O_EMAW  8422401
#define O_EMB   8684545

// scratch in the new_embedding slot (262144 floats, written LAST by fin).
// O_EMB is odd -> +1 float makes packed u64 8-byte aligned.
#define SE_PACKED 1        // u64 x 32768 -> floats [1, 65537)
#define SE_ESQ    65544
#define SE_ZSQ    66568    // 32768 floats
#define SE_HIST   99336    // 1024 ints
#define SE_DONE   100360   // 1 int

// ------- pre: zsq, esq, zero dw/hist/done/loss, init packed -------
__global__ void pre_kernel(const float* __restrict__ z, const float* __restrict__ E,
                           float* __restrict__ zsq, float* __restrict__ esq,
                           float* __restrict__ dw, int* __restrict__ hist,
                           unsigned long long* __restrict__ packed,
                           int* __restrict__ done, float* __restrict__ loss) {
    const int b = blockIdx.x;
    const int wave = threadIdx.x >> 6;
    const int lane = threadIdx.x & 63;
    if (b < NTOK / 4) {
        int token = b * 4 + wave;
        float4 v = ((const float4*)(z + (size_t)token * DIM))[lane];
        float s = v.x * v.x + v.y * v.y + v.z * v.z + v.w * v.w;
        #pragma unroll
        for (int off = 32; off > 0; off >>= 1) s += __shfl_down(s, off);
        if (lane == 0) zsq[token] = s;
        if (threadIdx.x < 4) packed[b * 4 + threadIdx.x] = ~0ull;
        if (b == 0 && threadIdx.x == 4) { done[0] = 0; loss[0] = 0.0f; }
    } else {
        int eb = b - NTOK / 4;                 // 0..255
        int k = eb * 4 + wave;
        float4 v = ((const float4*)(E + (size_t)k * DIM))[lane];
        float s = v.x * v.x + v.y * v.y + v.z * v.z + v.w * v.w;
        #pragma unroll
        for (int off = 32; off > 0; off >>= 1) s += __shfl_down(s, off);
        if (lane == 0) esq[k] = s;
        float4 zero4 = {0.f, 0.f, 0.f, 0.f};
        ((float4*)dw)[eb * 256 + threadIdx.x] = zero4;
        if (threadIdx.x < 4) hist[eb * 4 + threadIdx.x] = 0;
    }
}

// ---------------- fused distances + argmin (K-split + atomicMin) ----------
// d = fl(fl(||z||^2 + ||e||^2) - 2*z.e); positive -> float-bit order works.
// Pack (dist_bits<<32)|idx, u64 atomicMin = global min w/ first-index ties.
// Accumulation order per (i,j) identical to the passing rounds: dc asc, dg
// asc, x,y,z,w -> distances bit-identical.
// block 256 thr; tile 128 tok x 128 codes (1 of 8 K-chunks); 32-d chunks.
// thread: r=tid>>4 (8 tokens), c=tid&15 (8 codes c+16j).
// NO launch_bounds min-occupancy, NO reg prefetch: round 7's (256,3) +
// prefetch spilled acc[8][8] to scratch (WRITE_SIZE 8.4 GB, 12x slower).
// zs: 32-f rows, XOR swizzle slot=cf4^((row>>3)&7) -> zv reads = 4 distinct
// bank-quads/wave, 16-lane broadcast (free). es: 36-f rows -> ev 2-way (free).
// LDS 34.8 KB -> ~4 blocks/CU.
__global__ __launch_bounds__(256) void dist_argmin_kernel(
        const float* __restrict__ z, const float* __restrict__ E,
        const float* __restrict__ esq, const float* __restrict__ zsq,
        unsigned long long* __restrict__ packed) {
    __shared__ float zs[128 * 32];
    __shared__ float es[128 * 36];

    const int tid = threadIdx.x;
    const int r = tid >> 4;          // 0..15 -> tokens r*8 .. r*8+7
    const int c = tid & 15;          // codes c + 16*j, j=0..7
    const int ks   = blockIdx.x & 7;
    const int tok0 = (blockIdx.x >> 3) * 128;
    const int k0   = ks * 128;

    float An[8], sq[8];
    #pragma unroll
    for (int i = 0; i < 8; ++i) An[i] = zsq[tok0 + r * 8 + i];
    #pragma unroll
    for (int j = 0; j < 8; ++j) sq[j] = esq[k0 + c + 16 * j];

    // staging: thread covers rows srow+32q (q=0..3), fixed f4-col scf4
    const int srow = tid >> 3;       // 0..31
    const int scf4 = tid & 7;
    const float* zb = z + (size_t)(tok0 + srow) * DIM + scf4 * 4;
    const float* Eb = E + (size_t)(k0 + srow) * DIM + scf4 * 4;
    int zoff[4], eoff[4];
    #pragma unroll
    for (int q = 0; q < 4; ++q) {
        int row = srow + 32 * q;
        zoff[q] = row * 32 + ((scf4 ^ ((row >> 3) & 7)) << 2);
        eoff[q] = row * 36 + scf4 * 4;
    }

    float acc[8][8];
    #pragma unroll
    for (int i = 0; i < 8; ++i)
        #pragma unroll
        for (int j = 0; j < 8; ++j) acc[i][j] = 0.0f;

    for (int dc = 0; dc < 8; ++dc) {
        const int d0 = dc * 32;
        __syncthreads();
        #pragma unroll
        for (int q = 0; q < 4; ++q)
            *(float4*)(zs + zoff[q]) =
                *(const float4*)(zb + (size_t)q * 32 * DIM + d0);
        #pragma unroll
        for (int q = 0; q < 4; ++q)
            *(float4*)(es + eoff[q]) =
                *(const float4*)(Eb + (size_t)q * 32 * DIM + d0);
        __syncthreads();
        #pragma unroll
        for (int dg = 0; dg < 8; ++dg) {
            float4 zv[8];
            #pragma unroll
            for (int i = 0; i < 8; ++i)
                zv[i] = *(const float4*)(zs + (r * 8 + i) * 32 +
                                         ((dg ^ (r & 7)) << 2));
            #pragma unroll
            for (int j = 0; j < 8; ++j) {
                float4 ev = *(const float4*)(es + (c + 16 * j) * 36 + dg * 4);
                #pragma unroll
                for (int i = 0; i < 8; ++i) {
                    acc[i][j] = fmaf(zv[i].x, ev.x, acc[i][j]);
                    acc[i][j] = fmaf(zv[i].y, ev.y, acc[i][j]);
                    acc[i][j] = fmaf(zv[i].z, ev.z, acc[i][j]);
                    acc[i][j] = fmaf(zv[i].w, ev.w, acc[i][j]);
                }
            }
        }
    }
    // epilogue: mirror reference rounding sequence, local then cross-lane min
    #pragma unroll
    for (int i = 0; i < 8; ++i) {
        float v = 3.4e38f; int id = 0x7fffffff;
        #pragma unroll
        for (int j = 0; j < 8; ++j) {
            float S = An[i] + sq[j];
            float dv = S - 2.0f * acc[i][j];
            int gi = k0 + c + 16 * j;
            if (dv < v || (dv == v && gi < id)) { v = dv; id = gi; }
        }
        #pragma unroll
        for (int m = 1; m < 16; m <<= 1) {
            float ov = __shfl_xor(v, m);
            int   oi = __shfl_xor(id, m);
            if (ov < v || (ov == v && oi < id)) { v = ov; id = oi; }
        }
        if (c == 0) {
            unsigned long long p =
                ((unsigned long long)__float_as_uint(v) << 32) | (unsigned)id;
            atomicMin(&packed[tok0 + r * 8 + i], p);
        }
    }
}

// ------- mid: unpack idx, hist, quant gather, loss, dw atomics; -------
// ------- last block computes cluster-size (fenced done-counter).  -------
__global__ __launch_bounds__(256) void mid_kernel(
        const float* __restrict__ z, const float* __restrict__ E,
        const unsigned long long* __restrict__ packed,
        float* __restrict__ idx_out, int* __restrict__ hist,
        float* __restrict__ dw, float* __restrict__ quant,
        float* __restrict__ loss_acc, int* __restrict__ done,
        const float* __restrict__ ema_cs, float* __restrict__ cs_out) {
    __shared__ float ls[4];
    __shared__ int amlast;
    __shared__ float f[256];
    const int wave = threadIdx.x >> 6;
    const int lane = threadIdx.x & 63;
    const int token = blockIdx.x * 4 + wave;
    const int idx = (int)(unsigned)(packed[token] & 0xFFFFFFFFull);

    if (lane == 0) {
        idx_out[token] = (float)idx;
        atomicAdd(&hist[idx], 1);
    }

    const float4 ev = *(const float4*)(E + (size_t)idx * DIM + lane * 4);
    const float4 zv = *(const float4*)(z + (size_t)token * DIM + lane * 4);
    *(float4*)(quant + (size_t)token * DIM + lane * 4) = ev;

    float* dwp = dw + (size_t)idx * DIM + lane * 4;
    atomicAdd(dwp + 0, zv.x);
    atomicAdd(dwp + 1, zv.y);
    atomicAdd(dwp + 2, zv.z);
    atomicAdd(dwp + 3, zv.w);

    float dx = zv.x - ev.x, dy = zv.y - ev.y, dz = zv.z - ev.z, dww = zv.w - ev.w;
    float l = dx * dx + dy * dy + dz * dz + dww * dww;
    #pragma unroll
    for (int off = 32; off > 0; off >>= 1) l += __shfl_down(l, off);
    if (lane == 0) ls[wave] = l;
    __syncthreads();
    if (threadIdx.x == 0)
        atomicAdd(loss_acc, ls[0] + ls[1] + ls[2] + ls[3]);

    // last-block finale: cluster-size normalize
    __threadfence();
    __syncthreads();
    if (threadIdx.x == 0)
        amlast = (atomicAdd(done, 1) == (int)gridDim.x - 1);
    __syncthreads();
    if (amlast) {
        __threadfence();
        float pre4[4];
        float part = 0.0f;
        #pragma unroll
        for (int q = 0; q < 4; ++q) {
            int k = threadIdx.x * 4 + q;
            int cv = atomicAdd(&hist[k], 0);      // device-coherent read
            pre4[q] = ema_cs[k] * DECAY + (1.0f - DECAY) * (float)cv;
            part += pre4[q];
        }
        f[threadIdx.x] = part;
        __syncthreads();
        for (int s = 128; s > 0; s >>= 1) {
            if (threadIdx.x < s) f[threadIdx.x] += f[threadIdx.x + s];
            __syncthreads();
        }
        float n = f[0];
        #pragma unroll
        for (int q = 0; q < 4; ++q) {
            int k = threadIdx.x * 4 + q;
            cs_out[k] = (pre4[q] + EPSILON) / (n + KCODES * EPSILON) * n;
        }
    }
}

// ------- fin: new_ema_w & new_embedding (+ loss finalize) -------
__global__ __launch_bounds__(256) void fin_kernel(
        const float* __restrict__ ema_w, const float* __restrict__ cs,
        float* __restrict__ emaw_inout /* holds dw */, float* __restrict__ emb_out,
        float* __restrict__ loss_inout) {
    const int i = blockIdx.x * 256 + threadIdx.x;   // f4 index, 65536 total
    const int k = i >> 6;
    float4 d = ((const float4*)emaw_inout)[i];
    float4 w = ((const float4*)ema_w)[i];
    float4 nw;
    nw.x = w.x * DECAY + (1.0f - DECAY) * d.x;
    nw.y = w.y * DECAY + (1.0f - DECAY) * d.y;
    nw.z = w.z * DECAY + (1.0f - DECAY) * d.z;
    nw.w = w.w * DECAY + (1.0f - DECAY) * d.w;
    ((float4*)emaw_inout)[i] = nw;
    float inv = 1.0f / cs[k];
    float4 e; e.x = nw.x * inv; e.y = nw.y * inv; e.z = nw.z * inv; e.w = nw.w * inv;
    ((float4*)emb_out)[i] = e;
    if (i == 0)
        loss_inout[0] = COMMITMENT_COST * loss_inout[0] / (float)((size_t)NTOK * DIM);
}

extern "C" void kernel_launch(void* const* d_in, const int* in_sizes, int n_in,
                              void* d_out, int out_size, void* d_ws, size_t ws_size,
                              hipStream_t stream) {
    const float* z      = (const float*)d_in[0];
    const float* E      = (const float*)d_in[1];
    const float* ema_cs = (const float*)d_in[2];
    const float* ema_w  = (const float*)d_in[3];
    float* out = (float*)d_out;

    float* emb = out + O_EMB;
    unsigned long long* packed = (unsigned long long*)(emb + SE_PACKED);
    float* esq  = emb + SE_ESQ;
    float* zsq  = emb + SE_ZSQ;
    int*   hist = (int*)(emb + SE_HIST);
    int*   done = (int*)(emb + SE_DONE);

    pre_kernel<<<NTOK / 4 + KCODES / 4, 256, 0, stream>>>(
        z, E, zsq, esq, out + O_EMAW, hist, packed, done, out + O_LOSS);
    dist_argmin_kernel<<<(NTOK / 128) * 8, 256, 0, stream>>>(z, E, esq, zsq, packed);
    mid_kernel<<<NTOK / 4, 256, 0, stream>>>(z, E, packed, out + O_IDX, hist,
                                             out + O_EMAW, out + O_QUANT,
                                             out + O_LOSS, done, ema_cs, out + O_CS);
    fin_kernel<<<256, 256, 0, stream>>>(ema_w, out + O_CS, out + O_EMAW, emb,
                                        out + O_LOSS);
}

// Round 9
// 470.231 us; speedup vs baseline: 9.9872x; 2.2724x over previous
//
#include <hip/hip_runtime.h>
#include <math.h>

#define COMMITMENT_COST 0.25f
#define DECAY 0.99f
#define EPSILON 1e-05f
#define KCODES 1024
#define DIM 256
#define NTOK 32768

// out-buffer float offsets (concatenated return tuple)
#define O_QUANT 0
#define O_LOSS  8388608
#define O_IDX   8388609
#define O_CS    8421377
#define O_EMAW  8422401
#define O_EMB   8684545

// scratch in the new_embedding slot (262144 floats, written LAST by fin).
// O_EMB is odd -> +1 float makes packed u64 8-byte aligned.
#define SE_PACKED 1        // u64 x 32768 -> floats [1, 65537)
#define SE_ESQ    65544
#define SE_ZSQ    66568    // 32768 floats
#define SE_HIST   99336    // 1024 ints

// ------- pre: zsq, esq, zero dw/hist/loss, init packed -------
__global__ void pre_kernel(const float* __restrict__ z, const float* __restrict__ E,
                           float* __restrict__ zsq, float* __restrict__ esq,
                           float* __restrict__ dw, int* __restrict__ hist,
                           unsigned long long* __restrict__ packed,
                           float* __restrict__ loss) {
    const int b = blockIdx.x;
    const int wave = threadIdx.x >> 6;
    const int lane = threadIdx.x & 63;
    if (b < NTOK / 4) {
        int token = b * 4 + wave;
        float4 v = ((const float4*)(z + (size_t)token * DIM))[lane];
        float s = v.x * v.x + v.y * v.y + v.z * v.z + v.w * v.w;
        #pragma unroll
        for (int off = 32; off > 0; off >>= 1) s += __shfl_down(s, off);
        if (lane == 0) zsq[token] = s;
        if (threadIdx.x < 4) packed[b * 4 + threadIdx.x] = ~0ull;
        if (b == 0 && threadIdx.x == 4) loss[0] = 0.0f;
    } else {
        int eb = b - NTOK / 4;                 // 0..255
        int k = eb * 4 + wave;
        float4 v = ((const float4*)(E + (size_t)k * DIM))[lane];
        float s = v.x * v.x + v.y * v.y + v.z * v.z + v.w * v.w;
        #pragma unroll
        for (int off = 32; off > 0; off >>= 1) s += __shfl_down(s, off);
        if (lane == 0) esq[k] = s;
        float4 zero4 = {0.f, 0.f, 0.f, 0.f};
        ((float4*)dw)[eb * 256 + threadIdx.x] = zero4;
        if (threadIdx.x < 4) hist[eb * 4 + threadIdx.x] = 0;
    }
}

// ---------------- fused distances + argmin (K-split + atomicMin) ----------
// d = fl(fl(||z||^2 + ||e||^2) - 2*z.e); positive -> float-bit order works.
// Pack (dist_bits<<32)|idx, u64 atomicMin = global min w/ first-index ties.
// Accumulation order per (i,j) identical to all passing rounds: dc asc, dg
// asc, x,y,z,w -> distances bit-identical.
// block 256 thr; tile 128 tok x 128 codes (1 of 8 K-chunks); 32-d chunks.
// thread: r=tid>>4 (8 tokens), c=tid&15 (8 codes c+16j).
// NO launch_bounds min-occupancy, NO reg prefetch (round 7: spill disaster).
// zs: 32-f rows, XOR swizzle -> zv reads conflict-free; es: 36-f rows ->
// ev reads 2-way (free). LDS 34.8 KB -> ~4 blocks/CU.
__global__ __launch_bounds__(256) void dist_argmin_kernel(
        const float* __restrict__ z, const float* __restrict__ E,
        const float* __restrict__ esq, const float* __restrict__ zsq,
        unsigned long long* __restrict__ packed) {
    __shared__ float zs[128 * 32];
    __shared__ float es[128 * 36];

    const int tid = threadIdx.x;
    const int r = tid >> 4;          // 0..15 -> tokens r*8 .. r*8+7
    const int c = tid & 15;          // codes c + 16*j, j=0..7
    const int ks   = blockIdx.x & 7;
    const int tok0 = (blockIdx.x >> 3) * 128;
    const int k0   = ks * 128;

    float An[8], sq[8];
    #pragma unroll
    for (int i = 0; i < 8; ++i) An[i] = zsq[tok0 + r * 8 + i];
    #pragma unroll
    for (int j = 0; j < 8; ++j) sq[j] = esq[k0 + c + 16 * j];

    // staging: thread covers rows srow+32q (q=0..3), fixed f4-col scf4
    const int srow = tid >> 3;       // 0..31
    const int scf4 = tid & 7;
    const float* zb = z + (size_t)(tok0 + srow) * DIM + scf4 * 4;
    const float* Eb = E + (size_t)(k0 + srow) * DIM + scf4 * 4;
    int zoff[4], eoff[4];
    #pragma unroll
    for (int q = 0; q < 4; ++q) {
        int row = srow + 32 * q;
        zoff[q] = row * 32 + ((scf4 ^ ((row >> 3) & 7)) << 2);
        eoff[q] = row * 36 + scf4 * 4;
    }

    float acc[8][8];
    #pragma unroll
    for (int i = 0; i < 8; ++i)
        #pragma unroll
        for (int j = 0; j < 8; ++j) acc[i][j] = 0.0f;

    for (int dc = 0; dc < 8; ++dc) {
        const int d0 = dc * 32;
        __syncthreads();
        #pragma unroll
        for (int q = 0; q < 4; ++q)
            *(float4*)(zs + zoff[q]) =
                *(const float4*)(zb + (size_t)q * 32 * DIM + d0);
        #pragma unroll
        for (int q = 0; q < 4; ++q)
            *(float4*)(es + eoff[q]) =
                *(const float4*)(Eb + (size_t)q * 32 * DIM + d0);
        __syncthreads();
        #pragma unroll
        for (int dg = 0; dg < 8; ++dg) {
            float4 zv[8];
            #pragma unroll
            for (int i = 0; i < 8; ++i)
                zv[i] = *(const float4*)(zs + (r * 8 + i) * 32 +
                                         ((dg ^ (r & 7)) << 2));
            #pragma unroll
            for (int j = 0; j < 8; ++j) {
                float4 ev = *(const float4*)(es + (c + 16 * j) * 36 + dg * 4);
                #pragma unroll
                for (int i = 0; i < 8; ++i) {
                    acc[i][j] = fmaf(zv[i].x, ev.x, acc[i][j]);
                    acc[i][j] = fmaf(zv[i].y, ev.y, acc[i][j]);
                    acc[i][j] = fmaf(zv[i].z, ev.z, acc[i][j]);
                    acc[i][j] = fmaf(zv[i].w, ev.w, acc[i][j]);
                }
            }
        }
    }
    // epilogue: mirror reference rounding sequence, local then cross-lane min
    #pragma unroll
    for (int i = 0; i < 8; ++i) {
        float v = 3.4e38f; int id = 0x7fffffff;
        #pragma unroll
        for (int j = 0; j < 8; ++j) {
            float S = An[i] + sq[j];
            float dv = S - 2.0f * acc[i][j];
            int gi = k0 + c + 16 * j;
            if (dv < v || (dv == v && gi < id)) { v = dv; id = gi; }
        }
        #pragma unroll
        for (int m = 1; m < 16; m <<= 1) {
            float ov = __shfl_xor(v, m);
            int   oi = __shfl_xor(id, m);
            if (ov < v || (ov == v && oi < id)) { v = ov; id = oi; }
        }
        if (c == 0) {
            unsigned long long p =
                ((unsigned long long)__float_as_uint(v) << 32) | (unsigned)id;
            atomicMin(&packed[tok0 + r * 8 + i], p);
        }
    }
}

// ------- mid: unpack idx, hist, quant gather, loss, dw atomics -------
// NO __threadfence here (round 8: per-block device fence = L2 writeback on
// multi-XCD gfx950, 8192 x ~100ns = the entire 760us). Cross-kernel
// visibility comes from the dispatch boundary.
__global__ __launch_bounds__(256) void mid_kernel(
        const float* __restrict__ z, const float* __restrict__ E,
        const unsigned long long* __restrict__ packed,
        float* __restrict__ idx_out, int* __restrict__ hist,
        float* __restrict__ dw, float* __restrict__ quant,
        float* __restrict__ loss_acc) {
    __shared__ float ls[4];
    const int wave = threadIdx.x >> 6;
    const int lane = threadIdx.x & 63;
    const int token = blockIdx.x * 4 + wave;
    const int idx = (int)(unsigned)(packed[token] & 0xFFFFFFFFull);

    if (lane == 0) {
        idx_out[token] = (float)idx;
        atomicAdd(&hist[idx], 1);
    }

    const float4 ev = *(const float4*)(E + (size_t)idx * DIM + lane * 4);
    const float4 zv = *(const float4*)(z + (size_t)token * DIM + lane * 4);
    *(float4*)(quant + (size_t)token * DIM + lane * 4) = ev;

    float* dwp = dw + (size_t)idx * DIM + lane * 4;
    atomicAdd(dwp + 0, zv.x);
    atomicAdd(dwp + 1, zv.y);
    atomicAdd(dwp + 2, zv.z);
    atomicAdd(dwp + 3, zv.w);

    float dx = zv.x - ev.x, dy = zv.y - ev.y, dz = zv.z - ev.z, dww = zv.w - ev.w;
    float l = dx * dx + dy * dy + dz * dz + dww * dww;
    #pragma unroll
    for (int off = 32; off > 0; off >>= 1) l += __shfl_down(l, off);
    if (lane == 0) ls[wave] = l;
    __syncthreads();
    if (threadIdx.x == 0)
        atomicAdd(loss_acc, ls[0] + ls[1] + ls[2] + ls[3]);
}

// ------- cs: cluster-size normalize (1 block; dispatch boundary = sync) ---
__global__ __launch_bounds__(256) void cs_kernel(
        const int* __restrict__ hist, const float* __restrict__ ema_cs,
        float* __restrict__ cs_out) {
    __shared__ float f[256];
    float pre4[4];
    float part = 0.0f;
    #pragma unroll
    for (int q = 0; q < 4; ++q) {
        int k = threadIdx.x * 4 + q;
        pre4[q] = ema_cs[k] * DECAY + (1.0f - DECAY) * (float)hist[k];
        part += pre4[q];
    }
    f[threadIdx.x] = part;
    __syncthreads();
    for (int s = 128; s > 0; s >>= 1) {
        if (threadIdx.x < s) f[threadIdx.x] += f[threadIdx.x + s];
        __syncthreads();
    }
    float n = f[0];
    #pragma unroll
    for (int q = 0; q < 4; ++q) {
        int k = threadIdx.x * 4 + q;
        cs_out[k] = (pre4[q] + EPSILON) / (n + KCODES * EPSILON) * n;
    }
}

// ------- fin: new_ema_w & new_embedding (+ loss finalize) -------
__global__ __launch_bounds__(256) void fin_kernel(
        const float* __restrict__ ema_w, const float* __restrict__ cs,
        float* __restrict__ emaw_inout /* holds dw */, float* __restrict__ emb_out,
        float* __restrict__ loss_inout) {
    const int i = blockIdx.x * 256 + threadIdx.x;   // f4 index, 65536 total
    const int k = i >> 6;
    float4 d = ((const float4*)emaw_inout)[i];
    float4 w = ((const float4*)ema_w)[i];
    float4 nw;
    nw.x = w.x * DECAY + (1.0f - DECAY) * d.x;
    nw.y = w.y * DECAY + (1.0f - DECAY) * d.y;
    nw.z = w.z * DECAY + (1.0f - DECAY) * d.z;
    nw.w = w.w * DECAY + (1.0f - DECAY) * d.w;
    ((float4*)emaw_inout)[i] = nw;
    float inv = 1.0f / cs[k];
    float4 e; e.x = nw.x * inv; e.y = nw.y * inv; e.z = nw.z * inv; e.w = nw.w * inv;
    ((float4*)emb_out)[i] = e;
    if (i == 0)
        loss_inout[0] = COMMITMENT_COST * loss_inout[0] / (float)((size_t)NTOK * DIM);
}

extern "C" void kernel_launch(void* const* d_in, const int* in_sizes, int n_in,
                              void* d_out, int out_size, void* d_ws, size_t ws_size,
                              hipStream_t stream) {
    const float* z      = (const float*)d_in[0];
    const float* E      = (const float*)d_in[1];
    const float* ema_cs = (const float*)d_in[2];
    const float* ema_w  = (const float*)d_in[3];
    float* out = (float*)d_out;

    float* emb = out + O_EMB;
    unsigned long long* packed = (unsigned long long*)(emb + SE_PACKED);
    float* esq  = emb + SE_ESQ;
    float* zsq  = emb + SE_ZSQ;
    int*   hist = (int*)(emb + SE_HIST);

    pre_kernel<<<NTOK / 4 + KCODES / 4, 256, 0, stream>>>(
        z, E, zsq, esq, out + O_EMAW, hist, packed, out + O_LOSS);
    dist_argmin_kernel<<<(NTOK / 128) * 8, 256, 0, stream>>>(z, E, esq, zsq, packed);
    mid_kernel<<<NTOK / 4, 256, 0, stream>>>(z, E, packed, out + O_IDX, hist,
                                             out + O_EMAW, out + O_QUANT,
                                             out + O_LOSS);
    cs_kernel<<<1, 256, 0, stream>>>(hist, ema_cs, out + O_CS);
    fin_kernel<<<256, 256, 0, stream>>>(ema_w, out + O_CS, out + O_EMAW, emb,
                                        out + O_LOSS);
}